// Round 1
// baseline (843.236 us; speedup 1.0000x reference)
//
#include <hip/hip_runtime.h>

#define J 17
#define VO 289            // 17*17
#define NB 8192
#define DIN 2048
#define EPSB 1e-5f

// skeleton adjacency (incl. self), hard-coded from SKEL
__device__ __constant__ int d_deg[J] = {3,4,4,3,3,5,5,3,3,2,2,4,4,3,3,2,2};
__device__ __constant__ int d_nbr[J][5] = {
  {0,1,2,0,0},{0,1,2,3,0},{0,1,2,4,0},{1,3,5,0,0},{2,4,6,0,0},
  {3,5,6,7,11},{4,5,6,8,12},{5,7,9,0,0},{6,8,10,0,0},{7,9,0,0,0},
  {8,10,0,0,0},{5,11,12,13,0},{6,11,12,14,0},{11,13,15,0,0},{12,14,16,0,0},
  {13,15,0,0,0},{14,16,0,0,0}};

__global__ void zero_stats(float* p, int n) {
  int i = blockIdx.x*blockDim.x + threadIdx.x;
  int stride = gridDim.x*blockDim.x;
  for (; i < n; i += stride) p[i] = 0.f;
}

// -------- conv0: per-vertex GEMM [8192,2048]x[2048,17] + bias + BN-stat accum
// grid: (128 row-chunks of 64, 17 vertices), block 256 (4 waves).
// lane = 16 k-groups x 4 row-groups; each lane: 4 rows x 17 outs, k-slice of 16 per 128-chunk.
__global__ __launch_bounds__(256) void conv0_kernel(
    const float* __restrict__ feat, const float* __restrict__ W0,
    const float* __restrict__ b0, float* __restrict__ C,
    float* __restrict__ sS, float* __restrict__ sQ)
{
  const int v = blockIdx.y;
  const int tid = threadIdx.x;
  const int wv = tid >> 6, lane = tid & 63;
  const int kgrp = lane & 15, rgrp = lane >> 4;
  const int rowBase = blockIdx.x*64 + wv*16;

  __shared__ float wlds[128][20];   // pad 17->20: float4-aligned, conflict-light
  __shared__ float wstats[4][34];

  float acc[4][17];
  #pragma unroll
  for (int jj=0;jj<4;++jj)
    #pragma unroll
    for (int o=0;o<17;++o) acc[jj][o]=0.f;

  const float* gW = W0 + (size_t)v*DIN*J;
  const float* fbase = feat + (size_t)v*DIN;

  for (int kc=0;kc<16;++kc) {
    const float* gw = gW + kc*128*J;
    for (int idx=tid; idx<128*J; idx+=256) {
      int kk = idx/J, o = idx - kk*J;
      wlds[kk][o] = gw[idx];
    }
    __syncthreads();
    #pragma unroll
    for (int kk=0;kk<8;++kk) {
      const int kl = kk*16 + kgrp;
      const int kg = kc*128 + kl;
      float f[4];
      #pragma unroll
      for (int jj=0;jj<4;++jj)
        f[jj] = fbase[(size_t)(rowBase + rgrp + 4*jj)*(size_t)(DIN*J) + kg];
      float w[17];
      {
        const float4* wr = (const float4*)(&wlds[kl][0]);
        float4 a0=wr[0], a1=wr[1], a2=wr[2], a3=wr[3];
        w[0]=a0.x;  w[1]=a0.y;  w[2]=a0.z;  w[3]=a0.w;
        w[4]=a1.x;  w[5]=a1.y;  w[6]=a1.z;  w[7]=a1.w;
        w[8]=a2.x;  w[9]=a2.y;  w[10]=a2.z; w[11]=a2.w;
        w[12]=a3.x; w[13]=a3.y; w[14]=a3.z; w[15]=a3.w;
        w[16]=wlds[kl][16];
      }
      #pragma unroll
      for (int jj=0;jj<4;++jj)
        #pragma unroll
        for (int o=0;o<17;++o)
          acc[jj][o] += f[jj]*w[o];
    }
    __syncthreads();
  }

  // reduce over the 16 k-group lanes
  #pragma unroll
  for (int jj=0;jj<4;++jj)
    #pragma unroll
    for (int o=0;o<17;++o) {
      float x = acc[jj][o];
      x += __shfl_xor(x, 1);
      x += __shfl_xor(x, 2);
      x += __shfl_xor(x, 4);
      x += __shfl_xor(x, 8);
      acc[jj][o] = x;
    }

  float so[17], qo[17];
  #pragma unroll
  for (int o=0;o<17;++o){ so[o]=0.f; qo[o]=0.f; }
  if (kgrp==0) {
    #pragma unroll
    for (int jj=0;jj<4;++jj) {
      const int row = rowBase + rgrp + 4*jj;
      float* cp = C + (size_t)row*VO + v*J;
      #pragma unroll
      for (int o=0;o<17;++o) {
        float h = acc[jj][o] + b0[v*J+o];
        cp[o] = h;
        so[o] += h; qo[o] += h*h;
      }
    }
  }
  #pragma unroll
  for (int o=0;o<17;++o) {
    so[o] += __shfl_xor(so[o],16); so[o] += __shfl_xor(so[o],32);
    qo[o] += __shfl_xor(qo[o],16); qo[o] += __shfl_xor(qo[o],32);
  }
  if (lane==0) {
    #pragma unroll
    for (int o=0;o<17;++o){ wstats[wv][o]=so[o]; wstats[wv][17+o]=qo[o]; }
  }
  __syncthreads();
  if (tid<34) {
    float t = wstats[0][tid]+wstats[1][tid]+wstats[2][tid]+wstats[3][tid];
    if (tid<17) atomicAdd(&sS[v*J+tid], t);
    else        atomicAdd(&sQ[v*J+(tid-17)], t);
  }
}

// -------- chain: BN_j -> adjacency -> ReLU [-> +resid / store F] [-> conv_{j+1} + stats]
// grid 512 blocks x 16 rows, block 256 (4 waves, 1 row per wave per iter, 4 iters)
template<int RESID,int WRITEF,int CONV>
__global__ __launch_bounds__(256) void chain_kernel(
  const float* __restrict__ Cin, float* __restrict__ Cout,
  float* __restrict__ F,
  const float* __restrict__ sS, const float* __restrict__ sQ,
  const float* __restrict__ g, const float* __restrict__ be,
  const float* __restrict__ Wc, const float* __restrict__ bc,
  float* __restrict__ nS, float* __restrict__ nQ)
{
  __shared__ float wsm[J*J*J];
  __shared__ float bb[VO];
  __shared__ float aC[VO], cC[VO];
  __shared__ float hb1[4][VO], hb2[4][VO];
  __shared__ float ssum[VO], ssq[VO];
  const int tid = threadIdx.x, wv = tid>>6, lane = tid&63;

  if (CONV) {
    for (int i=tid;i<J*J*J;i+=256) wsm[i]=Wc[i];
    for (int i=tid;i<VO;i+=256) bb[i]=bc[i];
  }
  for (int i=tid;i<VO;i+=256) {
    float mu  = sS[i]*(1.f/NB);
    float var = sQ[i]*(1.f/NB) - mu*mu;
    float rs  = rsqrtf(var + EPSB);
    float A = rs*g[i];
    aC[i]=A; cC[i]=be[i]-mu*A;
    ssum[i]=0.f; ssq[i]=0.f;
  }
  __syncthreads();

  float sl[5], ql[5];
  #pragma unroll
  for (int s=0;s<5;++s){ sl[s]=0.f; ql[s]=0.f; }

  for (int it=0; it<4; ++it) {
    const int row = blockIdx.x*16 + it*4 + wv;
    const float* cr = Cin + (size_t)row*VO;
    #pragma unroll
    for (int s=0;s<5;++s) {
      int vo = lane + 64*s;
      if (vo<VO) hb1[wv][vo] = cr[vo]*aC[vo] + cC[vo];
    }
    __syncthreads();
    #pragma unroll
    for (int s=0;s<5;++s) {
      int vo = lane + 64*s;
      if (vo<VO) {
        int v = vo/J, o = vo - v*J;
        float a = 0.f;
        int dg = d_deg[v];
        for (int e=0;e<dg;++e) a += hb1[wv][d_nbr[v][e]*J + o];
        float h = a>0.f ? a : 0.f;
        size_t gi = (size_t)row*VO + vo;
        if (RESID)  h += F[gi];
        if (WRITEF) F[gi] = h;
        if (CONV) hb2[wv][vo] = h;
        else      Cout[gi] = h;
      }
    }
    __syncthreads();
    if (CONV) {
      #pragma unroll
      for (int s=0;s<5;++s) {
        int vo = lane + 64*s;
        if (vo<VO) {
          int v = vo/J, o = vo - v*J;
          float a = bb[vo];
          const float* wrow = &wsm[v*VO + o];
          const float* hrow = &hb2[wv][v*J];
          #pragma unroll
          for (int d=0;d<J;++d) a += hrow[d]*wrow[d*J];
          Cout[(size_t)row*VO + vo] = a;
          sl[s] += a; ql[s] += a*a;
        }
      }
    }
    __syncthreads();
  }

  if (CONV) {
    #pragma unroll
    for (int s=0;s<5;++s) {
      int vo = lane + 64*s;
      if (vo<VO) { atomicAdd(&ssum[vo], sl[s]); atomicAdd(&ssq[vo], ql[s]); }
    }
    __syncthreads();
    for (int i=tid;i<VO;i+=256) {
      atomicAdd(&nS[i], ssum[i]);
      atomicAdd(&nQ[i], ssq[i]);
    }
  }
}

extern "C" void kernel_launch(void* const* d_in, const int* in_sizes, int n_in,
                              void* d_out, int out_size, void* d_ws, size_t ws_size,
                              hipStream_t stream)
{
  (void)in_sizes; (void)n_in; (void)out_size; (void)ws_size;
  const float* img = (const float*)d_in[0];
  const float* W0  = (const float*)d_in[1];
  const float* b0  = (const float*)d_in[2];
  const float* g0  = (const float*)d_in[3];
  const float* be0 = (const float*)d_in[4];
  const float* Wr  = (const float*)d_in[5];
  const float* br  = (const float*)d_in[6];
  const float* gr  = (const float*)d_in[7];
  const float* ber = (const float*)d_in[8];

  float* ws = (float*)d_ws;
  float* sS = ws;                 // 9*289 used (4096 reserved)
  float* sQ = ws + 4096;          // 9*289 used (4096 reserved)
  float* Ca = ws + 8192;
  float* Cb = Ca + (size_t)NB*VO;
  float* F  = Cb + (size_t)NB*VO;
  float* out = (float*)d_out;

  zero_stats<<<8,256,0,stream>>>(ws, 8192);

  conv0_kernel<<<dim3(128,17),256,0,stream>>>(img, W0, b0, Ca, sS, sQ);

  const int W1 = J*J*J;
  // j=0: BN0(g0,be0) -> feat0 (store F), conv1 -> stats1
  chain_kernel<0,1,1><<<512,256,0,stream>>>(Ca, Cb, F, sS,        sQ,        g0,        be0,
                                            Wr+0*W1, br+0*VO, sS+1*VO, sQ+1*VO);
  // j=1
  chain_kernel<0,0,1><<<512,256,0,stream>>>(Cb, Ca, F, sS+1*VO, sQ+1*VO, gr+0*VO, ber+0*VO,
                                            Wr+1*W1, br+1*VO, sS+2*VO, sQ+2*VO);
  // j=2: resid + store F
  chain_kernel<1,1,1><<<512,256,0,stream>>>(Ca, Cb, F, sS+2*VO, sQ+2*VO, gr+1*VO, ber+1*VO,
                                            Wr+2*W1, br+2*VO, sS+3*VO, sQ+3*VO);
  // j=3
  chain_kernel<0,0,1><<<512,256,0,stream>>>(Cb, Ca, F, sS+3*VO, sQ+3*VO, gr+2*VO, ber+2*VO,
                                            Wr+3*W1, br+3*VO, sS+4*VO, sQ+4*VO);
  // j=4
  chain_kernel<1,1,1><<<512,256,0,stream>>>(Ca, Cb, F, sS+4*VO, sQ+4*VO, gr+3*VO, ber+3*VO,
                                            Wr+4*W1, br+4*VO, sS+5*VO, sQ+5*VO);
  // j=5
  chain_kernel<0,0,1><<<512,256,0,stream>>>(Cb, Ca, F, sS+5*VO, sQ+5*VO, gr+4*VO, ber+4*VO,
                                            Wr+5*W1, br+5*VO, sS+6*VO, sQ+6*VO);
  // j=6
  chain_kernel<1,1,1><<<512,256,0,stream>>>(Ca, Cb, F, sS+6*VO, sQ+6*VO, gr+5*VO, ber+5*VO,
                                            Wr+6*W1, br+6*VO, sS+7*VO, sQ+7*VO);
  // j=7
  chain_kernel<0,0,1><<<512,256,0,stream>>>(Cb, Ca, F, sS+7*VO, sQ+7*VO, gr+6*VO, ber+6*VO,
                                            Wr+7*W1, br+7*VO, sS+8*VO, sQ+8*VO);
  // j=8: BN8 -> adj -> relu -> + feat3 -> d_out
  chain_kernel<1,0,0><<<512,256,0,stream>>>(Ca, out, F, sS+8*VO, sQ+8*VO, gr+7*VO, ber+7*VO,
                                            nullptr, nullptr, nullptr, nullptr);
}

// Round 2
// 824.720 us; speedup vs baseline: 1.0225x; 1.0225x over previous
//
#include <hip/hip_runtime.h>

#define J 17
#define VO 289            // 17*17
#define NB 8192
#define DIN 2048
#define EPSB 1e-5f
#define CH 128            // conv0 k-chunk staged in LDS

// skeleton adjacency (incl. self), hard-coded from SKEL
__device__ __constant__ int d_deg[J] = {3,4,4,3,3,5,5,3,3,2,2,4,4,3,3,2,2};
__device__ __constant__ int d_nbr[J][5] = {
  {0,1,2,0,0},{0,1,2,3,0},{0,1,2,4,0},{1,3,5,0,0},{2,4,6,0,0},
  {3,5,6,7,11},{4,5,6,8,12},{5,7,9,0,0},{6,8,10,0,0},{7,9,0,0,0},
  {8,10,0,0,0},{5,11,12,13,0},{6,11,12,14,0},{11,13,15,0,0},{12,14,16,0,0},
  {13,15,0,0,0},{14,16,0,0,0}};

__global__ void zero_stats(float* p, int n) {
  int i = blockIdx.x*blockDim.x + threadIdx.x;
  int stride = gridDim.x*blockDim.x;
  for (; i < n; i += stride) p[i] = 0.f;
}

// -------- conv0: per-vertex GEMM [8192,2048]x[2048,17] + bias + BN-stat accum
// grid: (128 row-chunks of 64, 17 vertices), block 256 (4 waves).
// Wave handles 16 rows. lane: kgrp=lane&15 (16 k-quads -> 64 k per sub-iter),
// rgrp=lane>>4 (4 row-groups of 4 rows). Each lane: float4 feat loads
// (16 lanes = 256B contiguous), 4 rows x 17 outs accumulate.
__global__ __launch_bounds__(256) void conv0_kernel(
    const float* __restrict__ feat, const float* __restrict__ W0,
    const float* __restrict__ b0, float* __restrict__ C,
    float* __restrict__ sS, float* __restrict__ sQ)
{
  const int v = blockIdx.y;
  const int tid = threadIdx.x;
  const int wv = tid >> 6, lane = tid & 63;
  const int kgrp = lane & 15, rgrp = lane >> 4;
  const int rowBase = blockIdx.x*64 + wv*16 + rgrp*4;   // this lane's 4 rows

  __shared__ float wlds[2][CH][20];   // pad 17->20: 16B-aligned rows, 2-way-bank (free)
  __shared__ float wstats[4][34];

  float acc[4][17];
  #pragma unroll
  for (int jj=0;jj<4;++jj)
    #pragma unroll
    for (int o=0;o<17;++o) acc[jj][o]=0.f;

  const float* gW = W0 + (size_t)v*DIN*J;
  const float* frow[4];
  #pragma unroll
  for (int jj=0;jj<4;++jj)
    frow[jj] = feat + (size_t)(rowBase+jj)*(size_t)(J*DIN) + (size_t)v*DIN;

  // stage chunk 0
  for (int idx=tid; idx<CH*J; idx+=256) {
    int kk = idx/J, o = idx - kk*J;
    wlds[0][kk][o] = gW[idx];
  }
  __syncthreads();

  for (int kc=0;kc<DIN/CH;++kc) {
    const int buf = kc & 1;
    if (kc+1 < DIN/CH) {
      const float* gw = gW + (size_t)(kc+1)*CH*J;
      for (int idx=tid; idx<CH*J; idx+=256) {
        int kk = idx/J, o = idx - kk*J;
        wlds[buf^1][kk][o] = gw[idx];
      }
    }
    #pragma unroll
    for (int s=0;s<2;++s) {
      const int klocal = s*64 + 4*kgrp;
      const int kg = kc*CH + klocal;
      float4 f4[4];
      #pragma unroll
      for (int jj=0;jj<4;++jj)
        f4[jj] = *(const float4*)(frow[jj] + kg);
      #pragma unroll
      for (int q=0;q<4;++q) {
        float w[17];
        {
          const float4* wr = (const float4*)(&wlds[buf][klocal+q][0]);
          float4 a0=wr[0], a1=wr[1], a2=wr[2], a3=wr[3];
          w[0]=a0.x;  w[1]=a0.y;  w[2]=a0.z;  w[3]=a0.w;
          w[4]=a1.x;  w[5]=a1.y;  w[6]=a1.z;  w[7]=a1.w;
          w[8]=a2.x;  w[9]=a2.y;  w[10]=a2.z; w[11]=a2.w;
          w[12]=a3.x; w[13]=a3.y; w[14]=a3.z; w[15]=a3.w;
          w[16]=wlds[buf][klocal+q][16];
        }
        float fq[4];
        #pragma unroll
        for (int jj=0;jj<4;++jj) fq[jj] = ((const float*)&f4[jj])[q];
        #pragma unroll
        for (int jj=0;jj<4;++jj)
          #pragma unroll
          for (int o=0;o<17;++o)
            acc[jj][o] += fq[jj]*w[o];
      }
    }
    __syncthreads();
  }

  // reduce over the 16 k-group lanes (bits 0..3 of lane)
  #pragma unroll
  for (int jj=0;jj<4;++jj)
    #pragma unroll
    for (int o=0;o<17;++o) {
      float x = acc[jj][o];
      x += __shfl_xor(x, 1);
      x += __shfl_xor(x, 2);
      x += __shfl_xor(x, 4);
      x += __shfl_xor(x, 8);
      acc[jj][o] = x;
    }

  float so[17], qo[17];
  #pragma unroll
  for (int o=0;o<17;++o){ so[o]=0.f; qo[o]=0.f; }
  if (kgrp==0) {
    #pragma unroll
    for (int jj=0;jj<4;++jj) {
      const int row = rowBase + jj;
      float* cp = C + (size_t)row*VO + v*J;
      #pragma unroll
      for (int o=0;o<17;++o) {
        float h = acc[jj][o] + b0[v*J+o];
        cp[o] = h;
        so[o] += h; qo[o] += h*h;
      }
    }
  }
  #pragma unroll
  for (int o=0;o<17;++o) {
    so[o] += __shfl_xor(so[o],16); so[o] += __shfl_xor(so[o],32);
    qo[o] += __shfl_xor(qo[o],16); qo[o] += __shfl_xor(qo[o],32);
  }
  if (lane==0) {
    #pragma unroll
    for (int o=0;o<17;++o){ wstats[wv][o]=so[o]; wstats[wv][17+o]=qo[o]; }
  }
  __syncthreads();
  if (tid<34) {
    float t = wstats[0][tid]+wstats[1][tid]+wstats[2][tid]+wstats[3][tid];
    if (tid<17) atomicAdd(&sS[v*J+tid], t);
    else        atomicAdd(&sQ[v*J+(tid-17)], t);
  }
}

// -------- chain: BN_j -> adjacency -> ReLU [-> +resid / store F] [-> conv_{j+1} + stats]
// grid 512 blocks x 16 rows, block 256 (4 waves, 1 row per wave per iter, 4 iters)
template<int RESID,int WRITEF,int CONV>
__global__ __launch_bounds__(256) void chain_kernel(
  const float* __restrict__ Cin, float* __restrict__ Cout,
  float* __restrict__ F,
  const float* __restrict__ sS, const float* __restrict__ sQ,
  const float* __restrict__ g, const float* __restrict__ be,
  const float* __restrict__ Wc, const float* __restrict__ bc,
  float* __restrict__ nS, float* __restrict__ nQ)
{
  __shared__ float wsm[J*J*J];
  __shared__ float bb[VO];
  __shared__ float aC[VO], cC[VO];
  __shared__ float hb1[4][VO], hb2[4][VO];
  __shared__ float ssum[VO], ssq[VO];
  const int tid = threadIdx.x, wv = tid>>6, lane = tid&63;

  if (CONV) {
    for (int i=tid;i<J*J*J;i+=256) wsm[i]=Wc[i];
    for (int i=tid;i<VO;i+=256) bb[i]=bc[i];
  }
  for (int i=tid;i<VO;i+=256) {
    float mu  = sS[i]*(1.f/NB);
    float var = sQ[i]*(1.f/NB) - mu*mu;
    float rs  = rsqrtf(var + EPSB);
    float A = rs*g[i];
    aC[i]=A; cC[i]=be[i]-mu*A;
    ssum[i]=0.f; ssq[i]=0.f;
  }
  __syncthreads();

  float sl[5], ql[5];
  #pragma unroll
  for (int s=0;s<5;++s){ sl[s]=0.f; ql[s]=0.f; }

  for (int it=0; it<4; ++it) {
    const int row = blockIdx.x*16 + it*4 + wv;
    const float* cr = Cin + (size_t)row*VO;
    #pragma unroll
    for (int s=0;s<5;++s) {
      int vo = lane + 64*s;
      if (vo<VO) hb1[wv][vo] = cr[vo]*aC[vo] + cC[vo];
    }
    __syncthreads();
    #pragma unroll
    for (int s=0;s<5;++s) {
      int vo = lane + 64*s;
      if (vo<VO) {
        int v = vo/J, o = vo - v*J;
        float a = 0.f;
        int dg = d_deg[v];
        for (int e=0;e<dg;++e) a += hb1[wv][d_nbr[v][e]*J + o];
        float h = a>0.f ? a : 0.f;
        size_t gi = (size_t)row*VO + vo;
        if (RESID)  h += F[gi];
        if (WRITEF) F[gi] = h;
        if (CONV) hb2[wv][vo] = h;
        else      Cout[gi] = h;
      }
    }
    __syncthreads();
    if (CONV) {
      #pragma unroll
      for (int s=0;s<5;++s) {
        int vo = lane + 64*s;
        if (vo<VO) {
          int v = vo/J, o = vo - v*J;
          float a = bb[vo];
          const float* wrow = &wsm[v*VO + o];
          const float* hrow = &hb2[wv][v*J];
          #pragma unroll
          for (int d=0;d<J;++d) a += hrow[d]*wrow[d*J];
          Cout[(size_t)row*VO + vo] = a;
          sl[s] += a; ql[s] += a*a;
        }
      }
    }
    __syncthreads();
  }

  if (CONV) {
    #pragma unroll
    for (int s=0;s<5;++s) {
      int vo = lane + 64*s;
      if (vo<VO) { atomicAdd(&ssum[vo], sl[s]); atomicAdd(&ssq[vo], ql[s]); }
    }
    __syncthreads();
    for (int i=tid;i<VO;i+=256) {
      atomicAdd(&nS[i], ssum[i]);
      atomicAdd(&nQ[i], ssq[i]);
    }
  }
}

extern "C" void kernel_launch(void* const* d_in, const int* in_sizes, int n_in,
                              void* d_out, int out_size, void* d_ws, size_t ws_size,
                              hipStream_t stream)
{
  (void)in_sizes; (void)n_in; (void)out_size; (void)ws_size;
  const float* img = (const float*)d_in[0];
  const float* W0  = (const float*)d_in[1];
  const float* b0  = (const float*)d_in[2];
  const float* g0  = (const float*)d_in[3];
  const float* be0 = (const float*)d_in[4];
  const float* Wr  = (const float*)d_in[5];
  const float* br  = (const float*)d_in[6];
  const float* gr  = (const float*)d_in[7];
  const float* ber = (const float*)d_in[8];

  float* ws = (float*)d_ws;
  float* sS = ws;                 // 9*289 used (4096 reserved)
  float* sQ = ws + 4096;          // 9*289 used (4096 reserved)
  float* Ca = ws + 8192;
  float* Cb = Ca + (size_t)NB*VO;
  float* F  = Cb + (size_t)NB*VO;
  float* out = (float*)d_out;

  zero_stats<<<8,256,0,stream>>>(ws, 8192);

  conv0_kernel<<<dim3(128,17),256,0,stream>>>(img, W0, b0, Ca, sS, sQ);

  const int W1 = J*J*J;
  // j=0: BN0(g0,be0) -> feat0 (store F), conv1 -> stats1
  chain_kernel<0,1,1><<<512,256,0,stream>>>(Ca, Cb, F, sS,        sQ,        g0,        be0,
                                            Wr+0*W1, br+0*VO, sS+1*VO, sQ+1*VO);
  // j=1
  chain_kernel<0,0,1><<<512,256,0,stream>>>(Cb, Ca, F, sS+1*VO, sQ+1*VO, gr+0*VO, ber+0*VO,
                                            Wr+1*W1, br+1*VO, sS+2*VO, sQ+2*VO);
  // j=2: resid + store F
  chain_kernel<1,1,1><<<512,256,0,stream>>>(Ca, Cb, F, sS+2*VO, sQ+2*VO, gr+1*VO, ber+1*VO,
                                            Wr+2*W1, br+2*VO, sS+3*VO, sQ+3*VO);
  // j=3
  chain_kernel<0,0,1><<<512,256,0,stream>>>(Cb, Ca, F, sS+3*VO, sQ+3*VO, gr+2*VO, ber+2*VO,
                                            Wr+3*W1, br+3*VO, sS+4*VO, sQ+4*VO);
  // j=4
  chain_kernel<1,1,1><<<512,256,0,stream>>>(Ca, Cb, F, sS+4*VO, sQ+4*VO, gr+3*VO, ber+3*VO,
                                            Wr+4*W1, br+4*VO, sS+5*VO, sQ+5*VO);
  // j=5
  chain_kernel<0,0,1><<<512,256,0,stream>>>(Cb, Ca, F, sS+5*VO, sQ+5*VO, gr+4*VO, ber+4*VO,
                                            Wr+5*W1, br+5*VO, sS+6*VO, sQ+6*VO);
  // j=6
  chain_kernel<1,1,1><<<512,256,0,stream>>>(Ca, Cb, F, sS+6*VO, sQ+6*VO, gr+5*VO, ber+5*VO,
                                            Wr+6*W1, br+6*VO, sS+7*VO, sQ+7*VO);
  // j=7
  chain_kernel<0,0,1><<<512,256,0,stream>>>(Cb, Ca, F, sS+7*VO, sQ+7*VO, gr+6*VO, ber+6*VO,
                                            Wr+7*W1, br+7*VO, sS+8*VO, sQ+8*VO);
  // j=8: BN8 -> adj -> relu -> + feat3 -> d_out
  chain_kernel<1,0,0><<<512,256,0,stream>>>(Ca, out, F, sS+8*VO, sQ+8*VO, gr+7*VO, ber+7*VO,
                                            nullptr, nullptr, nullptr, nullptr);
}